// Round 7
// baseline (591.472 us; speedup 1.0000x reference)
//
#include <hip/hip_runtime.h>
#include <hip/hip_bf16.h>
#include <math.h>

#define N_NODES 10000
#define N_EDGES 640000
#define C 128
#define BF 16

typedef float vfloat4 __attribute__((ext_vector_type(4)));

__device__ __forceinline__ float gelu_exact(float z) {
    return 0.5f * z * (1.0f + erff(z * 0.70710678118654752f));
}

// --- K0: convert x to bf16 (2.56 MB -> L2-resident) ---
__global__ __launch_bounds__(256) void k_cvt(const float* __restrict__ x,
                                             __hip_bfloat16* __restrict__ xb) {
    int i = (blockIdx.x * 256 + threadIdx.x) * 4;
    float4 v = *(const float4*)(x + i);
    xb[i + 0] = __float2bfloat16(v.x);
    xb[i + 1] = __float2bfloat16(v.y);
    xb[i + 2] = __float2bfloat16(v.z);
    xb[i + 3] = __float2bfloat16(v.w);
}

// --- K1: degree counts ---
__global__ void k_deg(const int* __restrict__ ei, int* __restrict__ dr, int* __restrict__ dc) {
    int e = blockIdx.x * blockDim.x + threadIdx.x;
    if (e < N_EDGES) {
        atomicAdd(&dr[ei[e]], 1);
        atomicAdd(&dc[ei[N_EDGES + e]], 1);
    }
}

// --- K2: exclusive scan of dc -> off, plus inv-sqrt degrees ---
__global__ __launch_bounds__(1024) void k_scan(
    const int* __restrict__ dr, const int* __restrict__ dc,
    int* __restrict__ off, float* __restrict__ ir, float* __restrict__ ic)
{
    __shared__ int shp[1024];
    int t = threadIdx.x;
    int base = t * 10;
    int loc[10];
    int s = 0;
#pragma unroll
    for (int j = 0; j < 10; j++) {
        int i = base + j;
        int v = (i < N_NODES) ? dc[i] : 0;
        loc[j] = s;
        s += v;
    }
    shp[t] = s;
    __syncthreads();
    for (int st = 1; st < 1024; st <<= 1) {
        int a = (t >= st) ? shp[t - st] : 0;
        __syncthreads();
        shp[t] += a;
        __syncthreads();
    }
    int excl = shp[t] - s;
#pragma unroll
    for (int j = 0; j < 10; j++) {
        int i = base + j;
        if (i < N_NODES) {
            off[i] = excl + loc[j];
            ir[i] = rsqrtf((float)(dr[i] + 1));
            ic[i] = rsqrtf((float)(dc[i] + 1));
        }
    }
    if (t == 1023) off[N_NODES] = shp[1023];
}

// --- K3 (full path): scatter+permute. Coalesced reads, random (fire-and-forget)
//     non-temporal writes of permuted edge data into destination-bucket order. ---
__global__ __launch_bounds__(256) void k_fill(
    const int* __restrict__ ei, const float* __restrict__ ew,
    const float* __restrict__ ea,
    const int* __restrict__ off, int* __restrict__ cur,
    const float* __restrict__ ir, const float* __restrict__ ic,
    float* __restrict__ eap, int* __restrict__ rr, float* __restrict__ ss)
{
    int e = blockIdx.x * 256 + threadIdx.x;          // grid covers N_EDGES exactly
    int r = ei[e];
    int c = ei[N_EDGES + e];
    int pos = atomicAdd(&cur[c], 1);
    int slot = off[c] + pos;
    float s = ir[r] * ic[c] * ew[e];
    __builtin_nontemporal_store(r, rr + slot);
    __builtin_nontemporal_store(s, ss + slot);
    const vfloat4* src = (const vfloat4*)(ea + (size_t)e * BF);
    vfloat4* dst = (vfloat4*)(eap + (size_t)slot * BF);
#pragma unroll
    for (int j = 0; j < 4; j++) {
        vfloat4 q = __builtin_nontemporal_load(src + j);
        __builtin_nontemporal_store(q, dst + j);
    }
}

// --- K4 (full path): one block (512 thr = 4 groups x 128 ch) per node.
//     All per-edge streams sequential; 2-stage software pipeline. ---
__global__ __launch_bounds__(512) void k_node2(
    const __hip_bfloat16* __restrict__ xb,
    const float* __restrict__ eap,
    const int* __restrict__ rr, const float* __restrict__ ss,
    const float* __restrict__ Wb, const float* __restrict__ bb,
    const float* __restrict__ ir, const float* __restrict__ ic,
    const int* __restrict__ off,
    const float* __restrict__ Wl, const float* __restrict__ bl,
    float* __restrict__ out)
{
    int n = blockIdx.x;
    int t = threadIdx.x & (C - 1);
    int g = threadIdx.x >> 7;

    float icn = ic[n];
    float wb[BF];
#pragma unroll
    for (int k = 0; k < BF; k++) wb[k] = Wb[(size_t)k * C + t];
    float bbt = bb[t];

    float acc = 0.0f;
    if (g == 0) {
        acc = gelu_exact(__bfloat162float(xb[(size_t)n * C + t])) * (ir[n] * icn);
    }

    int o1 = off[n + 1];
    int i = off[n] + g;

    // stage regs
    int rP = 0; float sP = 0.0f, xvP = 0.0f;
    float4 qa0 = {}, qa1 = {}, qa2 = {}, qa3 = {};
    if (i < o1) {
        rP = rr[i]; sP = ss[i];
        const float4* ep = (const float4*)(eap + (size_t)i * BF);
        qa0 = ep[0]; qa1 = ep[1]; qa2 = ep[2]; qa3 = ep[3];
        xvP = __bfloat162float(xb[(size_t)rP * C + t]);
    }
    while (i < o1) {
        float s = sP, xv = xvP;
        float4 q0 = qa0, q1 = qa1, q2 = qa2, q3 = qa3;
        i += 4;
        if (i < o1) {                         // prefetch next stage
            rP = rr[i]; sP = ss[i];
            const float4* ep = (const float4*)(eap + (size_t)i * BF);
            qa0 = ep[0]; qa1 = ep[1]; qa2 = ep[2]; qa3 = ep[3];
            xvP = __bfloat162float(xb[(size_t)rP * C + t]);
        }
        float emb = bbt;
        emb = fmaf(q0.x, wb[0], emb);  emb = fmaf(q0.y, wb[1], emb);
        emb = fmaf(q0.z, wb[2], emb);  emb = fmaf(q0.w, wb[3], emb);
        emb = fmaf(q1.x, wb[4], emb);  emb = fmaf(q1.y, wb[5], emb);
        emb = fmaf(q1.z, wb[6], emb);  emb = fmaf(q1.w, wb[7], emb);
        emb = fmaf(q2.x, wb[8], emb);  emb = fmaf(q2.y, wb[9], emb);
        emb = fmaf(q2.z, wb[10], emb); emb = fmaf(q2.w, wb[11], emb);
        emb = fmaf(q3.x, wb[12], emb); emb = fmaf(q3.y, wb[13], emb);
        emb = fmaf(q3.z, wb[14], emb); emb = fmaf(q3.w, wb[15], emb);
        acc = fmaf(gelu_exact(xv + emb), s, acc);
    }

    __shared__ float shp[4][C];
    __shared__ float shs[C];
    shp[g][t] = acc;
    __syncthreads();
    if (threadIdx.x < C) {
        int k = threadIdx.x;
        shs[k] = shp[0][k] + shp[1][k] + shp[2][k] + shp[3][k];
    }
    __syncthreads();
    float o = 0.0f;
    int k0 = g * 32;
#pragma unroll 8
    for (int j = 0; j < 32; j++) {
        int k = k0 + j;
        o = fmaf(shs[k], Wl[(size_t)k * C + t], o);
    }
    shp[g][t] = o;
    __syncthreads();
    if (threadIdx.x < C) {
        int c = threadIdx.x;
        out[(size_t)n * C + c] = bl[c] + shp[0][c] + shp[1][c] + shp[2][c] + shp[3][c];
    }
}

// ---------------- fallback path (round-5 structure, ws-lean) ----------------
__global__ void k_scatter(const int* __restrict__ ei, const int* __restrict__ off,
                          int* __restrict__ cur, int* __restrict__ bucket) {
    int e = blockIdx.x * blockDim.x + threadIdx.x;
    if (e < N_EDGES) {
        int c = ei[N_EDGES + e];
        int pos = atomicAdd(&cur[c], 1);
        bucket[off[c] + pos] = e;
    }
}

template <bool USEBF>
__global__ __launch_bounds__(512) void k_node_fb(
    const float* __restrict__ x, const __hip_bfloat16* __restrict__ xb,
    const float* __restrict__ ea, const float* __restrict__ ew,
    const float* __restrict__ Wb, const float* __restrict__ bb,
    const int* __restrict__ ei,
    const float* __restrict__ ir, const float* __restrict__ ic,
    const int* __restrict__ off, const int* __restrict__ bucket,
    const float* __restrict__ Wl, const float* __restrict__ bl,
    float* __restrict__ out)
{
    int n = blockIdx.x;
    int t = threadIdx.x & (C - 1);
    int g = threadIdx.x >> 7;
    float icn = ic[n];
    float wb[BF];
#pragma unroll
    for (int k = 0; k < BF; k++) wb[k] = Wb[(size_t)k * C + t];
    float bbt = bb[t];
    float acc = 0.0f;
    if (g == 0) {
        float xv = USEBF ? __bfloat162float(xb[(size_t)n * C + t]) : x[(size_t)n * C + t];
        acc = gelu_exact(xv) * (ir[n] * icn);
    }
    int o0 = off[n], o1 = off[n + 1];
    for (int i = o0 + g; i < o1; i += 4) {
        int e = __builtin_amdgcn_readfirstlane(bucket[i]);
        int r = ei[e];
        float s = ir[r] * icn * ew[e];
        const float4* eapt = (const float4*)(ea + (size_t)e * BF);
        float4 q0 = eapt[0], q1 = eapt[1], q2 = eapt[2], q3 = eapt[3];
        float emb = bbt;
        emb = fmaf(q0.x, wb[0], emb);  emb = fmaf(q0.y, wb[1], emb);
        emb = fmaf(q0.z, wb[2], emb);  emb = fmaf(q0.w, wb[3], emb);
        emb = fmaf(q1.x, wb[4], emb);  emb = fmaf(q1.y, wb[5], emb);
        emb = fmaf(q1.z, wb[6], emb);  emb = fmaf(q1.w, wb[7], emb);
        emb = fmaf(q2.x, wb[8], emb);  emb = fmaf(q2.y, wb[9], emb);
        emb = fmaf(q2.z, wb[10], emb); emb = fmaf(q2.w, wb[11], emb);
        emb = fmaf(q3.x, wb[12], emb); emb = fmaf(q3.y, wb[13], emb);
        emb = fmaf(q3.z, wb[14], emb); emb = fmaf(q3.w, wb[15], emb);
        float xv = USEBF ? __bfloat162float(xb[(size_t)r * C + t]) : x[(size_t)r * C + t];
        acc = fmaf(gelu_exact(xv + emb), s, acc);
    }
    __shared__ float shp[4][C];
    __shared__ float shs[C];
    shp[g][t] = acc;
    __syncthreads();
    if (threadIdx.x < C) {
        int k = threadIdx.x;
        shs[k] = shp[0][k] + shp[1][k] + shp[2][k] + shp[3][k];
    }
    __syncthreads();
    float o = 0.0f;
    int k0 = g * 32;
#pragma unroll 8
    for (int j = 0; j < 32; j++) {
        int k = k0 + j;
        o = fmaf(shs[k], Wl[(size_t)k * C + t], o);
    }
    shp[g][t] = o;
    __syncthreads();
    if (threadIdx.x < C) {
        int c = threadIdx.x;
        out[(size_t)n * C + c] = bl[c] + shp[0][c] + shp[1][c] + shp[2][c] + shp[3][c];
    }
}

extern "C" void kernel_launch(void* const* d_in, const int* in_sizes, int n_in,
                              void* d_out, int out_size, void* d_ws, size_t ws_size,
                              hipStream_t stream) {
    const float* x  = (const float*)d_in[0];
    const float* ea = (const float*)d_in[1];
    const float* ew = (const float*)d_in[2];
    const float* Wb = (const float*)d_in[3];
    const float* bb = (const float*)d_in[4];
    const float* Wl = (const float*)d_in[5];
    const float* bl = (const float*)d_in[6];
    const int*   ei = (const int*)d_in[7];
    float* out = (float*)d_out;

    // full layout (u32 units): xb 640000 | eap 10,240,000 | rr 640000 | ss 640000 |
    //                          off 10304 | dr 10240 | dc 10240 | cur 10240 | ir 10240 | ic 10240
    const size_t need_full = (size_t)(640000 + 10240000 + 640000 + 640000 + 10304 + 5 * 10240) * 4;
    const size_t need_bf   = (size_t)(640000 + 640000 + 10304 + 5 * 10240) * 4;

    unsigned* w32 = (unsigned*)d_ws;
    if (ws_size >= need_full) {
        __hip_bfloat16* xb = (__hip_bfloat16*)w32;
        float* eap = (float*)(w32 + 640000);
        int*   rr  = (int*)(w32 + 640000 + 10240000);
        float* ss  = (float*)(rr + 640000);
        int*   off = (int*)(ss + 640000);
        int*   dr  = off + 10304;
        int*   dc  = dr + 10240;
        int*   cur = dc + 10240;
        float* ir  = (float*)(cur + 10240);
        float* ic  = ir + 10240;

        hipMemsetAsync(dr, 0, 3 * 10240 * sizeof(int), stream);   // dr, dc, cur
        k_cvt<<<1250, 256, 0, stream>>>(x, xb);
        k_deg<<<(N_EDGES + 255) / 256, 256, 0, stream>>>(ei, dr, dc);
        k_scan<<<1, 1024, 0, stream>>>(dr, dc, off, ir, ic);
        k_fill<<<N_EDGES / 256, 256, 0, stream>>>(ei, ew, ea, off, cur, ir, ic, eap, rr, ss);
        k_node2<<<N_NODES, 512, 0, stream>>>(xb, eap, rr, ss, Wb, bb, ir, ic, off, Wl, bl, out);
    } else {
        bool usebf = ws_size >= need_bf;
        __hip_bfloat16* xb = (__hip_bfloat16*)w32;
        int* bucket = (int*)(w32 + (usebf ? 640000 : 0));
        int* off    = bucket + 640000;
        int* dr     = off + 10304;
        int* dc     = dr + 10240;
        int* cur    = dc + 10240;
        float* ir   = (float*)(cur + 10240);
        float* ic   = ir + 10240;

        hipMemsetAsync(dr, 0, 3 * 10240 * sizeof(int), stream);
        if (usebf) k_cvt<<<1250, 256, 0, stream>>>(x, xb);
        k_deg<<<(N_EDGES + 255) / 256, 256, 0, stream>>>(ei, dr, dc);
        k_scan<<<1, 1024, 0, stream>>>(dr, dc, off, ir, ic);
        k_scatter<<<(N_EDGES + 255) / 256, 256, 0, stream>>>(ei, off, cur, bucket);
        if (usebf)
            k_node_fb<true><<<N_NODES, 512, 0, stream>>>(x, xb, ea, ew, Wb, bb, ei, ir, ic, off, bucket, Wl, bl, out);
        else
            k_node_fb<false><<<N_NODES, 512, 0, stream>>>(x, xb, ea, ew, Wb, bb, ei, ir, ic, off, bucket, Wl, bl, out);
    }
}

// Round 8
// 377.040 us; speedup vs baseline: 1.5687x; 1.5687x over previous
//
#include <hip/hip_runtime.h>
#include <hip/hip_bf16.h>
#include <math.h>

#define N_NODES 10000
#define N_EDGES 640000
#define C 128
#define BF 16
#define EPB 16   // edges per k_msg block

__device__ __forceinline__ float gelu_exact(float z) {
    return 0.5f * z * (1.0f + erff(z * 0.70710678118654752f));
}

// --- K0: convert x to bf16 (2.56 MB -> L2-resident) ---
__global__ __launch_bounds__(256) void k_cvt(const float* __restrict__ x,
                                             __hip_bfloat16* __restrict__ xb) {
    int i = (blockIdx.x * 256 + threadIdx.x) * 4;
    float4 v = *(const float4*)(x + i);
    xb[i + 0] = __float2bfloat16(v.x);
    xb[i + 1] = __float2bfloat16(v.y);
    xb[i + 2] = __float2bfloat16(v.z);
    xb[i + 3] = __float2bfloat16(v.w);
}

// --- K1: degree counts ---
__global__ void k_deg(const int* __restrict__ ei, int* __restrict__ dr, int* __restrict__ dc) {
    int e = blockIdx.x * blockDim.x + threadIdx.x;
    if (e < N_EDGES) {
        atomicAdd(&dr[ei[e]], 1);
        atomicAdd(&dc[ei[N_EDGES + e]], 1);
    }
}

// --- K2: exclusive scan of dc -> off, plus inv-sqrt degrees ---
__global__ __launch_bounds__(1024) void k_scan(
    const int* __restrict__ dr, const int* __restrict__ dc,
    int* __restrict__ off, float* __restrict__ ir, float* __restrict__ ic)
{
    __shared__ int shp[1024];
    int t = threadIdx.x;
    int base = t * 10;
    int loc[10];
    int s = 0;
#pragma unroll
    for (int j = 0; j < 10; j++) {
        int i = base + j;
        int v = (i < N_NODES) ? dc[i] : 0;
        loc[j] = s;
        s += v;
    }
    shp[t] = s;
    __syncthreads();
    for (int st = 1; st < 1024; st <<= 1) {
        int a = (t >= st) ? shp[t - st] : 0;
        __syncthreads();
        shp[t] += a;
        __syncthreads();
    }
    int excl = shp[t] - s;
#pragma unroll
    for (int j = 0; j < 10; j++) {
        int i = base + j;
        if (i < N_NODES) {
            off[i] = excl + loc[j];
            ir[i] = rsqrtf((float)(dr[i] + 1));
            ic[i] = rsqrtf((float)(dc[i] + 1));
        }
    }
    if (t == 1023) off[N_NODES] = shp[1023];
}

// --- K3 (full path): edge-parallel message kernel. Coalesced edge-order reads,
//     all per-edge math here, full-line NT scatter of finished bf16 msg rows. ---
__global__ __launch_bounds__(128) void k_msg(
    const int* __restrict__ ei, const float* __restrict__ ew,
    const float* __restrict__ ea,
    const __hip_bfloat16* __restrict__ xb,
    const float* __restrict__ Wb, const float* __restrict__ bb,
    const int* __restrict__ off, int* __restrict__ cur,
    const float* __restrict__ ir, const float* __restrict__ ic,
    __hip_bfloat16* __restrict__ msg)
{
    int e0 = blockIdx.x * EPB;                 // grid = N_EDGES/EPB exactly
    int t = threadIdx.x;                       // channel 0..127

    __shared__ int   sl_slot[EPB];
    __shared__ float sl_s[EPB];
    __shared__ int   sl_r[EPB];
    if (t < EPB) {
        int e = e0 + t;
        int r = ei[e];
        int c = ei[N_EDGES + e];
        int pos = atomicAdd(&cur[c], 1);
        sl_slot[t] = off[c] + pos;
        sl_s[t] = ir[r] * ic[c] * ew[e];
        sl_r[t] = r;
    }

    // per-channel W_bond column + bias (hoisted over EPB edges)
    float wb[BF];
#pragma unroll
    for (int k = 0; k < BF; k++) wb[k] = Wb[(size_t)k * C + t];
    float bbt = bb[t];
    __syncthreads();

#pragma unroll 4
    for (int j = 0; j < EPB; j++) {
        int e = e0 + j;
        const float4* eap = (const float4*)(ea + (size_t)e * BF);
        float4 q0 = eap[0], q1 = eap[1], q2 = eap[2], q3 = eap[3];  // wave-broadcast

        float emb = bbt;
        emb = fmaf(q0.x, wb[0], emb);  emb = fmaf(q0.y, wb[1], emb);
        emb = fmaf(q0.z, wb[2], emb);  emb = fmaf(q0.w, wb[3], emb);
        emb = fmaf(q1.x, wb[4], emb);  emb = fmaf(q1.y, wb[5], emb);
        emb = fmaf(q1.z, wb[6], emb);  emb = fmaf(q1.w, wb[7], emb);
        emb = fmaf(q2.x, wb[8], emb);  emb = fmaf(q2.y, wb[9], emb);
        emb = fmaf(q2.z, wb[10], emb); emb = fmaf(q2.w, wb[11], emb);
        emb = fmaf(q3.x, wb[12], emb); emb = fmaf(q3.y, wb[13], emb);
        emb = fmaf(q3.z, wb[14], emb); emb = fmaf(q3.w, wb[15], emb);

        int r = sl_r[j];
        float xv = __bfloat162float(xb[(size_t)r * C + t]);
        float m = gelu_exact(xv + emb) * sl_s[j];
        __hip_bfloat16 h = __float2bfloat16(m);
        unsigned short hv;
        __builtin_memcpy(&hv, &h, 2);
        __builtin_nontemporal_store(hv,
            (unsigned short*)(msg + (size_t)sl_slot[j] * C) + t);  // full-line scatter
    }
}

// --- K4 (full path): per-node sequential sum of bf16 msg rows + self-loop
//     + fused GEMV epilogue. ---
__global__ __launch_bounds__(128) void k_sum(
    const __hip_bfloat16* __restrict__ msg,
    const __hip_bfloat16* __restrict__ xb,
    const float* __restrict__ ir, const float* __restrict__ ic,
    const int* __restrict__ off,
    const float* __restrict__ Wl, const float* __restrict__ bl,
    float* __restrict__ out)
{
    int n = blockIdx.x;
    int t = threadIdx.x;

    float acc = gelu_exact(__bfloat162float(xb[(size_t)n * C + t])) * (ir[n] * ic[n]);

    int o0 = off[n];
    int cnt = off[n + 1] - o0;
    const __hip_bfloat16* p = msg + (size_t)o0 * C + t;

    float a0 = 0.f, a1 = 0.f, a2 = 0.f, a3 = 0.f;
    int i = 0;
    for (; i + 4 <= cnt; i += 4) {
        a0 += __bfloat162float(p[(size_t)(i + 0) * C]);
        a1 += __bfloat162float(p[(size_t)(i + 1) * C]);
        a2 += __bfloat162float(p[(size_t)(i + 2) * C]);
        a3 += __bfloat162float(p[(size_t)(i + 3) * C]);
    }
    for (; i < cnt; i++) a0 += __bfloat162float(p[(size_t)i * C]);
    acc += (a0 + a1) + (a2 + a3);

    __shared__ float shs[C];
    shs[t] = acc;
    __syncthreads();

    float o = bl[t];
    const float4* shv = (const float4*)shs;
#pragma unroll 4
    for (int k4 = 0; k4 < C / 4; k4++) {
        float4 sv = shv[k4];                    // ds_read_b128 broadcast
        int k = k4 * 4;
        o = fmaf(sv.x, Wl[(size_t)(k + 0) * C + t], o);
        o = fmaf(sv.y, Wl[(size_t)(k + 1) * C + t], o);
        o = fmaf(sv.z, Wl[(size_t)(k + 2) * C + t], o);
        o = fmaf(sv.w, Wl[(size_t)(k + 3) * C + t], o);
    }
    out[(size_t)n * C + t] = o;
}

// ---------------- fallback path (round-5 structure, ws-lean) ----------------
__global__ void k_scatter(const int* __restrict__ ei, const int* __restrict__ off,
                          int* __restrict__ cur, int* __restrict__ bucket) {
    int e = blockIdx.x * blockDim.x + threadIdx.x;
    if (e < N_EDGES) {
        int c = ei[N_EDGES + e];
        int pos = atomicAdd(&cur[c], 1);
        bucket[off[c] + pos] = e;
    }
}

template <bool USEBF>
__global__ __launch_bounds__(512) void k_node_fb(
    const float* __restrict__ x, const __hip_bfloat16* __restrict__ xb,
    const float* __restrict__ ea, const float* __restrict__ ew,
    const float* __restrict__ Wb, const float* __restrict__ bb,
    const int* __restrict__ ei,
    const float* __restrict__ ir, const float* __restrict__ ic,
    const int* __restrict__ off, const int* __restrict__ bucket,
    const float* __restrict__ Wl, const float* __restrict__ bl,
    float* __restrict__ out)
{
    int n = blockIdx.x;
    int t = threadIdx.x & (C - 1);
    int g = threadIdx.x >> 7;
    float icn = ic[n];
    float wb[BF];
#pragma unroll
    for (int k = 0; k < BF; k++) wb[k] = Wb[(size_t)k * C + t];
    float bbt = bb[t];
    float acc = 0.0f;
    if (g == 0) {
        float xv = USEBF ? __bfloat162float(xb[(size_t)n * C + t]) : x[(size_t)n * C + t];
        acc = gelu_exact(xv) * (ir[n] * icn);
    }
    int o0 = off[n], o1 = off[n + 1];
    for (int i = o0 + g; i < o1; i += 4) {
        int e = __builtin_amdgcn_readfirstlane(bucket[i]);
        int r = ei[e];
        float s = ir[r] * icn * ew[e];
        const float4* eapt = (const float4*)(ea + (size_t)e * BF);
        float4 q0 = eapt[0], q1 = eapt[1], q2 = eapt[2], q3 = eapt[3];
        float emb = bbt;
        emb = fmaf(q0.x, wb[0], emb);  emb = fmaf(q0.y, wb[1], emb);
        emb = fmaf(q0.z, wb[2], emb);  emb = fmaf(q0.w, wb[3], emb);
        emb = fmaf(q1.x, wb[4], emb);  emb = fmaf(q1.y, wb[5], emb);
        emb = fmaf(q1.z, wb[6], emb);  emb = fmaf(q1.w, wb[7], emb);
        emb = fmaf(q2.x, wb[8], emb);  emb = fmaf(q2.y, wb[9], emb);
        emb = fmaf(q2.z, wb[10], emb); emb = fmaf(q2.w, wb[11], emb);
        emb = fmaf(q3.x, wb[12], emb); emb = fmaf(q3.y, wb[13], emb);
        emb = fmaf(q3.z, wb[14], emb); emb = fmaf(q3.w, wb[15], emb);
        float xv = USEBF ? __bfloat162float(xb[(size_t)r * C + t]) : x[(size_t)r * C + t];
        acc = fmaf(gelu_exact(xv + emb), s, acc);
    }
    __shared__ float shp[4][C];
    __shared__ float shs[C];
    shp[g][t] = acc;
    __syncthreads();
    if (threadIdx.x < C) {
        int k = threadIdx.x;
        shs[k] = shp[0][k] + shp[1][k] + shp[2][k] + shp[3][k];
    }
    __syncthreads();
    float o = 0.0f;
    int k0 = g * 32;
#pragma unroll 8
    for (int j = 0; j < 32; j++) {
        int k = k0 + j;
        o = fmaf(shs[k], Wl[(size_t)k * C + t], o);
    }
    shp[g][t] = o;
    __syncthreads();
    if (threadIdx.x < C) {
        int c = threadIdx.x;
        out[(size_t)n * C + c] = bl[c] + shp[0][c] + shp[1][c] + shp[2][c] + shp[3][c];
    }
}

extern "C" void kernel_launch(void* const* d_in, const int* in_sizes, int n_in,
                              void* d_out, int out_size, void* d_ws, size_t ws_size,
                              hipStream_t stream) {
    const float* x  = (const float*)d_in[0];
    const float* ea = (const float*)d_in[1];
    const float* ew = (const float*)d_in[2];
    const float* Wb = (const float*)d_in[3];
    const float* bb = (const float*)d_in[4];
    const float* Wl = (const float*)d_in[5];
    const float* bl = (const float*)d_in[6];
    const int*   ei = (const int*)d_in[7];
    float* out = (float*)d_out;

    // full layout: msg (bf16, 640000*128 = 81,920,000 elem) placed first for
    // 256 B alignment | xb 1,280,000 bf16 | off 10304 u32 | dr/dc/cur 3x10240 |
    // ir/ic 2x10240 f32
    const size_t msg_elems = (size_t)N_EDGES * C;                 // 81,920,000
    const size_t need_full = msg_elems * 2 + 1280000ull * 2 + (10304 + 5 * 10240) * 4;
    const size_t need_bf   = (size_t)(640000 + 640000 + 10304 + 5 * 10240) * 4;

    if (ws_size >= need_full) {
        __hip_bfloat16* msg = (__hip_bfloat16*)d_ws;
        __hip_bfloat16* xb  = msg + msg_elems;
        int*   off = (int*)(xb + 1280000);
        int*   dr  = off + 10304;
        int*   dc  = dr + 10240;
        int*   cur = dc + 10240;
        float* ir  = (float*)(cur + 10240);
        float* ic  = ir + 10240;

        hipMemsetAsync(dr, 0, 3 * 10240 * sizeof(int), stream);   // dr, dc, cur
        k_cvt<<<1250, 256, 0, stream>>>(x, xb);
        k_deg<<<(N_EDGES + 255) / 256, 256, 0, stream>>>(ei, dr, dc);
        k_scan<<<1, 1024, 0, stream>>>(dr, dc, off, ir, ic);
        k_msg<<<N_EDGES / EPB, 128, 0, stream>>>(ei, ew, ea, xb, Wb, bb, off, cur, ir, ic, msg);
        k_sum<<<N_NODES, 128, 0, stream>>>(msg, xb, ir, ic, off, Wl, bl, out);
    } else {
        bool usebf = ws_size >= need_bf;
        unsigned* w32 = (unsigned*)d_ws;
        __hip_bfloat16* xb = (__hip_bfloat16*)w32;
        int* bucket = (int*)(w32 + (usebf ? 640000 : 0));
        int* off    = bucket + 640000;
        int* dr     = off + 10304;
        int* dc     = dr + 10240;
        int* cur    = dc + 10240;
        float* ir   = (float*)(cur + 10240);
        float* ic   = ir + 10240;

        hipMemsetAsync(dr, 0, 3 * 10240 * sizeof(int), stream);
        if (usebf) k_cvt<<<1250, 256, 0, stream>>>(x, xb);
        k_deg<<<(N_EDGES + 255) / 256, 256, 0, stream>>>(ei, dr, dc);
        k_scan<<<1, 1024, 0, stream>>>(dr, dc, off, ir, ic);
        k_scatter<<<(N_EDGES + 255) / 256, 256, 0, stream>>>(ei, off, cur, bucket);
        if (usebf)
            k_node_fb<true><<<N_NODES, 512, 0, stream>>>(x, xb, ea, ew, Wb, bb, ei, ir, ic, off, bucket, Wl, bl, out);
        else
            k_node_fb<false><<<N_NODES, 512, 0, stream>>>(x, xb, ea, ew, Wb, bb, ei, ir, ic, off, bucket, Wl, bl, out);
    }
}

// Round 9
// 320.439 us; speedup vs baseline: 1.8458x; 1.1766x over previous
//
#include <hip/hip_runtime.h>
#include <hip/hip_bf16.h>
#include <math.h>

#define N_NODES 10000
#define N_EDGES 640000
#define C 128
#define BF 16
#define EPB 16   // edges per k_msg block

typedef float vfloat4 __attribute__((ext_vector_type(4)));

__device__ __forceinline__ float2 bf2_to_f2(unsigned u) {
    union { unsigned x; float f; } lo, hi;
    lo.x = (u & 0xffffu) << 16;
    hi.x = u & 0xffff0000u;
    float2 r; r.x = lo.f; r.y = hi.f; return r;
}

// tanh-approx GELU: z*sigmoid(1.5957691*(z+0.044715 z^3)), exp2 domain.
// |err vs exact-erf gelu| <= ~4e-4; branchless, saturates correctly at +/-inf.
__device__ __forceinline__ float fast_gelu(float z) {
    float z2 = z * z;
    float p  = z * fmaf(0.044715f, z2, 1.0f);
    float e  = __builtin_amdgcn_exp2f(-2.3022082f * p);   // exp2(-2*0.79788456*log2e * p)
    float r  = __builtin_amdgcn_rcpf(1.0f + e);
    return z * r;
}

// --- K0: convert x to bf16 (2.56 MB -> L2-resident) ---
__global__ __launch_bounds__(256) void k_cvt(const float* __restrict__ x,
                                             __hip_bfloat16* __restrict__ xb) {
    int i = (blockIdx.x * 256 + threadIdx.x) * 4;
    float4 v = *(const float4*)(x + i);
    xb[i + 0] = __float2bfloat16(v.x);
    xb[i + 1] = __float2bfloat16(v.y);
    xb[i + 2] = __float2bfloat16(v.z);
    xb[i + 3] = __float2bfloat16(v.w);
}

// --- K1: degree counts ---
__global__ void k_deg(const int* __restrict__ ei, int* __restrict__ dr, int* __restrict__ dc) {
    int e = blockIdx.x * blockDim.x + threadIdx.x;
    if (e < N_EDGES) {
        atomicAdd(&dr[ei[e]], 1);
        atomicAdd(&dc[ei[N_EDGES + e]], 1);
    }
}

// --- K2: exclusive scan of dc -> off, plus inv-sqrt degrees ---
__global__ __launch_bounds__(1024) void k_scan(
    const int* __restrict__ dr, const int* __restrict__ dc,
    int* __restrict__ off, float* __restrict__ ir, float* __restrict__ ic)
{
    __shared__ int shp[1024];
    int t = threadIdx.x;
    int base = t * 10;
    int loc[10];
    int s = 0;
#pragma unroll
    for (int j = 0; j < 10; j++) {
        int i = base + j;
        int v = (i < N_NODES) ? dc[i] : 0;
        loc[j] = s;
        s += v;
    }
    shp[t] = s;
    __syncthreads();
    for (int st = 1; st < 1024; st <<= 1) {
        int a = (t >= st) ? shp[t - st] : 0;
        __syncthreads();
        shp[t] += a;
        __syncthreads();
    }
    int excl = shp[t] - s;
#pragma unroll
    for (int j = 0; j < 10; j++) {
        int i = base + j;
        if (i < N_NODES) {
            off[i] = excl + loc[j];
            ir[i] = rsqrtf((float)(dr[i] + 1));
            ic[i] = rsqrtf((float)(dc[i] + 1));
        }
    }
    if (t == 1023) off[N_NODES] = shp[1023];
}

// --- K3: edge-parallel message kernel. Coalesced NT edge-order reads,
//     all per-edge math here, full-line NT scatter of finished bf16 msg rows. ---
__global__ __launch_bounds__(128) void k_msg(
    const int* __restrict__ ei, const float* __restrict__ ew,
    const float* __restrict__ ea,
    const __hip_bfloat16* __restrict__ xb,
    const float* __restrict__ Wb, const float* __restrict__ bb,
    const int* __restrict__ off, int* __restrict__ cur,
    const float* __restrict__ ir, const float* __restrict__ ic,
    __hip_bfloat16* __restrict__ msg)
{
    int e0 = blockIdx.x * EPB;                 // grid = N_EDGES/EPB exactly
    int t = threadIdx.x;                       // channel 0..127

    __shared__ int   sl_slot[EPB];
    __shared__ float sl_s[EPB];
    __shared__ int   sl_r[EPB];
    if (t < EPB) {
        int e = e0 + t;
        int r = ei[e];
        int c = ei[N_EDGES + e];
        int pos = atomicAdd(&cur[c], 1);
        sl_slot[t] = off[c] + pos;
        sl_s[t] = ir[r] * ic[c] * ew[e];
        sl_r[t] = r;
    }

    // per-channel W_bond column + bias (hoisted over EPB edges)
    float wb[BF];
#pragma unroll
    for (int k = 0; k < BF; k++) wb[k] = Wb[(size_t)k * C + t];
    float bbt = bb[t];
    __syncthreads();

#pragma unroll 4
    for (int j = 0; j < EPB; j++) {
        int e = e0 + j;
        const vfloat4* eap = (const vfloat4*)(ea + (size_t)e * BF);
        vfloat4 q0 = __builtin_nontemporal_load(eap + 0);   // read-once stream:
        vfloat4 q1 = __builtin_nontemporal_load(eap + 1);   // NT protects xb in L2
        vfloat4 q2 = __builtin_nontemporal_load(eap + 2);
        vfloat4 q3 = __builtin_nontemporal_load(eap + 3);

        float emb = bbt;
        emb = fmaf(q0.x, wb[0], emb);  emb = fmaf(q0.y, wb[1], emb);
        emb = fmaf(q0.z, wb[2], emb);  emb = fmaf(q0.w, wb[3], emb);
        emb = fmaf(q1.x, wb[4], emb);  emb = fmaf(q1.y, wb[5], emb);
        emb = fmaf(q1.z, wb[6], emb);  emb = fmaf(q1.w, wb[7], emb);
        emb = fmaf(q2.x, wb[8], emb);  emb = fmaf(q2.y, wb[9], emb);
        emb = fmaf(q2.z, wb[10], emb); emb = fmaf(q2.w, wb[11], emb);
        emb = fmaf(q3.x, wb[12], emb); emb = fmaf(q3.y, wb[13], emb);
        emb = fmaf(q3.z, wb[14], emb); emb = fmaf(q3.w, wb[15], emb);

        int r = sl_r[j];
        float xv = __bfloat162float(xb[(size_t)r * C + t]);
        float m = fast_gelu(xv + emb) * sl_s[j];
        __hip_bfloat16 h = __float2bfloat16(m);
        unsigned short hv;
        __builtin_memcpy(&hv, &h, 2);
        __builtin_nontemporal_store(hv,
            (unsigned short*)(msg + (size_t)sl_slot[j] * C) + t);  // full-line scatter
    }
}

// --- K4: per-node sum of bf16 msg rows (4 row-groups x 64 channel-pairs,
//     NT uint loads) + self-loop + split GEMV epilogue. ---
__global__ __launch_bounds__(256) void k_sum(
    const __hip_bfloat16* __restrict__ msg,
    const __hip_bfloat16* __restrict__ xb,
    const float* __restrict__ ir, const float* __restrict__ ic,
    const int* __restrict__ off,
    const float* __restrict__ Wl, const float* __restrict__ bl,
    float* __restrict__ out)
{
    int n = blockIdx.x;
    int t = threadIdx.x;
    int g = t >> 6;           // row group 0..3
    int p = t & 63;           // channel pair (channels 2p, 2p+1)

    int o0 = off[n];
    int cnt = off[n + 1] - o0;
    const unsigned* base = (const unsigned*)(msg + (size_t)o0 * C) + p;

    float ax0 = 0.f, ay0 = 0.f, ax1 = 0.f, ay1 = 0.f;
    int i = g;
    for (; i + 4 < cnt; i += 8) {
        unsigned u0 = __builtin_nontemporal_load(base + (size_t)i * (C / 2));
        unsigned u1 = __builtin_nontemporal_load(base + (size_t)(i + 4) * (C / 2));
        float2 f0 = bf2_to_f2(u0);
        float2 f1 = bf2_to_f2(u1);
        ax0 += f0.x; ay0 += f0.y;
        ax1 += f1.x; ay1 += f1.y;
    }
    if (i < cnt) {
        float2 f0 = bf2_to_f2(__builtin_nontemporal_load(base + (size_t)i * (C / 2)));
        ax0 += f0.x; ay0 += f0.y;
    }
    ax0 += ax1; ay0 += ay1;

    __shared__ float2 shp[4][64];
    __shared__ float  shs[C];
    __shared__ float  sho[2][C];
    shp[g][p] = make_float2(ax0, ay0);
    __syncthreads();
    if (t < 64) {
        float2 s0 = shp[0][t], s1 = shp[1][t], s2 = shp[2][t], s3 = shp[3][t];
        float vx = (s0.x + s1.x) + (s2.x + s3.x);
        float vy = (s0.y + s1.y) + (s2.y + s3.y);
        float sl = ir[n] * ic[n];                      // self-loop norm
        float2 xf = bf2_to_f2(*((const unsigned*)(xb + (size_t)n * C) + t));
        shs[2 * t]     = vx + fast_gelu(xf.x) * sl;
        shs[2 * t + 1] = vy + fast_gelu(xf.y) * sl;
    }
    __syncthreads();

    // GEMV: half = k-range [64*half, 64*half+64), ch = output channel
    int ch = t & 127, half = t >> 7;
    float o = 0.f;
    const float4* shv = (const float4*)shs + half * 16;
    const float* wcol = Wl + (size_t)(half * 64) * C + ch;
#pragma unroll 8
    for (int k4 = 0; k4 < 16; k4++) {
        float4 sv = shv[k4];                           // ds_read_b128 broadcast
        o = fmaf(sv.x, wcol[(size_t)(k4 * 4 + 0) * C], o);
        o = fmaf(sv.y, wcol[(size_t)(k4 * 4 + 1) * C], o);
        o = fmaf(sv.z, wcol[(size_t)(k4 * 4 + 2) * C], o);
        o = fmaf(sv.w, wcol[(size_t)(k4 * 4 + 3) * C], o);
    }
    sho[half][ch] = o;
    __syncthreads();
    if (t < C) out[(size_t)n * C + t] = bl[t] + sho[0][t] + sho[1][t];
}

// ---------------- fallback path (round-5 structure, ws-lean) ----------------
__global__ void k_scatter(const int* __restrict__ ei, const int* __restrict__ off,
                          int* __restrict__ cur, int* __restrict__ bucket) {
    int e = blockIdx.x * blockDim.x + threadIdx.x;
    if (e < N_EDGES) {
        int c = ei[N_EDGES + e];
        int pos = atomicAdd(&cur[c], 1);
        bucket[off[c] + pos] = e;
    }
}

template <bool USEBF>
__global__ __launch_bounds__(512) void k_node_fb(
    const float* __restrict__ x, const __hip_bfloat16* __restrict__ xb,
    const float* __restrict__ ea, const float* __restrict__ ew,
    const float* __restrict__ Wb, const float* __restrict__ bb,
    const int* __restrict__ ei,
    const float* __restrict__ ir, const float* __restrict__ ic,
    const int* __restrict__ off, const int* __restrict__ bucket,
    const float* __restrict__ Wl, const float* __restrict__ bl,
    float* __restrict__ out)
{
    int n = blockIdx.x;
    int t = threadIdx.x & (C - 1);
    int g = threadIdx.x >> 7;
    float icn = ic[n];
    float wb[BF];
#pragma unroll
    for (int k = 0; k < BF; k++) wb[k] = Wb[(size_t)k * C + t];
    float bbt = bb[t];
    float acc = 0.0f;
    if (g == 0) {
        float xv = USEBF ? __bfloat162float(xb[(size_t)n * C + t]) : x[(size_t)n * C + t];
        acc = fast_gelu(xv) * (ir[n] * icn);
    }
    int o0 = off[n], o1 = off[n + 1];
    for (int i = o0 + g; i < o1; i += 4) {
        int e = __builtin_amdgcn_readfirstlane(bucket[i]);
        int r = ei[e];
        float s = ir[r] * icn * ew[e];
        const float4* eapt = (const float4*)(ea + (size_t)e * BF);
        float4 q0 = eapt[0], q1 = eapt[1], q2 = eapt[2], q3 = eapt[3];
        float emb = bbt;
        emb = fmaf(q0.x, wb[0], emb);  emb = fmaf(q0.y, wb[1], emb);
        emb = fmaf(q0.z, wb[2], emb);  emb = fmaf(q0.w, wb[3], emb);
        emb = fmaf(q1.x, wb[4], emb);  emb = fmaf(q1.y, wb[5], emb);
        emb = fmaf(q1.z, wb[6], emb);  emb = fmaf(q1.w, wb[7], emb);
        emb = fmaf(q2.x, wb[8], emb);  emb = fmaf(q2.y, wb[9], emb);
        emb = fmaf(q2.z, wb[10], emb); emb = fmaf(q2.w, wb[11], emb);
        emb = fmaf(q3.x, wb[12], emb); emb = fmaf(q3.y, wb[13], emb);
        emb = fmaf(q3.z, wb[14], emb); emb = fmaf(q3.w, wb[15], emb);
        float xv = USEBF ? __bfloat162float(xb[(size_t)r * C + t]) : x[(size_t)r * C + t];
        acc = fmaf(fast_gelu(xv + emb), s, acc);
    }
    __shared__ float shp[4][C];
    __shared__ float shs[C];
    shp[g][t] = acc;
    __syncthreads();
    if (threadIdx.x < C) {
        int k = threadIdx.x;
        shs[k] = shp[0][k] + shp[1][k] + shp[2][k] + shp[3][k];
    }
    __syncthreads();
    float o = 0.0f;
    int k0 = g * 32;
#pragma unroll 8
    for (int j = 0; j < 32; j++) {
        int k = k0 + j;
        o = fmaf(shs[k], Wl[(size_t)k * C + t], o);
    }
    shp[g][t] = o;
    __syncthreads();
    if (threadIdx.x < C) {
        int c = threadIdx.x;
        out[(size_t)n * C + c] = bl[c] + shp[0][c] + shp[1][c] + shp[2][c] + shp[3][c];
    }
}

extern "C" void kernel_launch(void* const* d_in, const int* in_sizes, int n_in,
                              void* d_out, int out_size, void* d_ws, size_t ws_size,
                              hipStream_t stream) {
    const float* x  = (const float*)d_in[0];
    const float* ea = (const float*)d_in[1];
    const float* ew = (const float*)d_in[2];
    const float* Wb = (const float*)d_in[3];
    const float* bb = (const float*)d_in[4];
    const float* Wl = (const float*)d_in[5];
    const float* bl = (const float*)d_in[6];
    const int*   ei = (const int*)d_in[7];
    float* out = (float*)d_out;

    const size_t msg_elems = (size_t)N_EDGES * C;                 // 81,920,000
    const size_t need_full = msg_elems * 2 + 1280000ull * 2 + (10304 + 5 * 10240) * 4;
    const size_t need_bf   = (size_t)(640000 + 640000 + 10304 + 5 * 10240) * 4;

    if (ws_size >= need_full) {
        __hip_bfloat16* msg = (__hip_bfloat16*)d_ws;
        __hip_bfloat16* xb  = msg + msg_elems;
        int*   off = (int*)(xb + 1280000);
        int*   dr  = off + 10304;
        int*   dc  = dr + 10240;
        int*   cur = dc + 10240;
        float* ir  = (float*)(cur + 10240);
        float* ic  = ir + 10240;

        hipMemsetAsync(dr, 0, 3 * 10240 * sizeof(int), stream);   // dr, dc, cur
        k_cvt<<<1250, 256, 0, stream>>>(x, xb);
        k_deg<<<(N_EDGES + 255) / 256, 256, 0, stream>>>(ei, dr, dc);
        k_scan<<<1, 1024, 0, stream>>>(dr, dc, off, ir, ic);
        k_msg<<<N_EDGES / EPB, 128, 0, stream>>>(ei, ew, ea, xb, Wb, bb, off, cur, ir, ic, msg);
        k_sum<<<N_NODES, 256, 0, stream>>>(msg, xb, ir, ic, off, Wl, bl, out);
    } else {
        bool usebf = ws_size >= need_bf;
        unsigned* w32 = (unsigned*)d_ws;
        __hip_bfloat16* xb = (__hip_bfloat16*)w32;
        int* bucket = (int*)(w32 + (usebf ? 640000 : 0));
        int* off    = bucket + 640000;
        int* dr     = off + 10304;
        int* dc     = dr + 10240;
        int* cur    = dc + 10240;
        float* ir   = (float*)(cur + 10240);
        float* ic   = ir + 10240;

        hipMemsetAsync(dr, 0, 3 * 10240 * sizeof(int), stream);
        if (usebf) k_cvt<<<1250, 256, 0, stream>>>(x, xb);
        k_deg<<<(N_EDGES + 255) / 256, 256, 0, stream>>>(ei, dr, dc);
        k_scan<<<1, 1024, 0, stream>>>(dr, dc, off, ir, ic);
        k_scatter<<<(N_EDGES + 255) / 256, 256, 0, stream>>>(ei, off, cur, bucket);
        if (usebf)
            k_node_fb<true><<<N_NODES, 512, 0, stream>>>(x, xb, ea, ew, Wb, bb, ei, ir, ic, off, bucket, Wl, bl, out);
        else
            k_node_fb<false><<<N_NODES, 512, 0, stream>>>(x, xb, ea, ew, Wb, bb, ei, ir, ic, off, bucket, Wl, bl, out);
    }
}